// Round 1
// baseline (1221.168 us; speedup 1.0000x reference)
//
#include <hip/hip_runtime.h>
#include <math.h>

#define N_NODES 50000
#define N_EDGES 800000
#define DIM 128
#define NHEADS 8
#define HDIM 16
#define LN_EPS 1e-5f
#define LEAKY 0.2f
#define NPB 16   // nodes per block for the node-level GEMM kernels

// ---------------- monotonic float<->uint mapping for atomicMax on floats ----
__device__ __forceinline__ unsigned mono(float f) {
    unsigned b = __float_as_uint(f);
    return (b & 0x80000000u) ? ~b : (b | 0x80000000u);
}
__device__ __forceinline__ float unmono(unsigned u) {
    return __uint_as_float((u & 0x80000000u) ? (u & 0x7FFFFFFFu) : ~u);
}

// ---------------- K1: U1 = W4@W1, U2 = W4@W2, c = W4@W3 (tiny) --------------
__global__ __launch_bounds__(128) void k_prep(
    const float* __restrict__ W1, const float* __restrict__ W2,
    const float* __restrict__ W3, const float* __restrict__ W4,
    float* __restrict__ U1, float* __restrict__ U2, float* __restrict__ c) {
    int h = blockIdx.x;       // 0..7
    int k = threadIdx.x;      // 0..127
    float a1 = 0.f, a2 = 0.f;
    for (int d = 0; d < DIM; ++d) {
        float w4 = W4[h * DIM + d];
        a1 += w4 * W1[d * DIM + k];
        a2 += w4 * W2[d * DIM + k];
    }
    U1[h * DIM + k] = a1;
    U2[h * DIM + k] = a2;
    __shared__ float red[DIM];
    red[k] = W4[h * DIM + k] * W3[k];
    __syncthreads();
    if (k == 0) {
        float s = 0.f;
        for (int i = 0; i < DIM; ++i) s += red[i];
        c[h] = s;
    }
}

// ---------------- K2: V = H@Wv^T, R = H@res_w^T + res_b ---------------------
__global__ __launch_bounds__(128) void k_node_vr(
    const float* __restrict__ H, const float* __restrict__ Wv,
    const float* __restrict__ Wres, const float* __restrict__ bres,
    float* __restrict__ V, float* __restrict__ R) {
    __shared__ __align__(16) float Hs[NPB][DIM];
    int d = threadIdx.x;
    int n0 = blockIdx.x * NPB;
    #pragma unroll
    for (int i = 0; i < NPB; ++i) Hs[i][d] = H[(size_t)(n0 + i) * DIM + d];
    __syncthreads();
    float accv[NPB], accr[NPB];
    #pragma unroll
    for (int i = 0; i < NPB; ++i) { accv[i] = 0.f; accr[i] = 0.f; }
    const float4* Wv4 = reinterpret_cast<const float4*>(Wv + (size_t)d * DIM);
    const float4* Wr4 = reinterpret_cast<const float4*>(Wres + (size_t)d * DIM);
    #pragma unroll 4
    for (int k4 = 0; k4 < DIM / 4; ++k4) {
        float4 wv = Wv4[k4];
        float4 wr = Wr4[k4];
        #pragma unroll
        for (int i = 0; i < NPB; ++i) {
            float4 hh = *reinterpret_cast<const float4*>(&Hs[i][k4 * 4]);
            accv[i] += hh.x * wv.x + hh.y * wv.y + hh.z * wv.z + hh.w * wv.w;
            accr[i] += hh.x * wr.x + hh.y * wr.y + hh.z * wr.z + hh.w * wr.w;
        }
    }
    float rb = bres[d];
    #pragma unroll
    for (int i = 0; i < NPB; ++i) {
        V[(size_t)(n0 + i) * DIM + d] = accv[i];
        R[(size_t)(n0 + i) * DIM + d] = accr[i] + rb;
    }
}

// ---------------- K3: A1 = H@U1^T, A2 = H@U2^T  (wave per node) -------------
__global__ __launch_bounds__(256) void k_node_a(
    const float* __restrict__ H, const float* __restrict__ U1,
    const float* __restrict__ U2, float* __restrict__ A1, float* __restrict__ A2) {
    int node = (blockIdx.x * 256 + threadIdx.x) >> 6;
    int lane = threadIdx.x & 63;
    if (node >= N_NODES) return;
    float h0 = H[(size_t)node * DIM + lane];
    float h1 = H[(size_t)node * DIM + 64 + lane];
    #pragma unroll
    for (int h = 0; h < NHEADS; ++h) {
        float p1 = h0 * U1[h * DIM + lane] + h1 * U1[h * DIM + 64 + lane];
        float p2 = h0 * U2[h * DIM + lane] + h1 * U2[h * DIM + 64 + lane];
        #pragma unroll
        for (int off = 32; off > 0; off >>= 1) {
            p1 += __shfl_down(p1, off, 64);
            p2 += __shfl_down(p2, off, 64);
        }
        if (lane == 0) {
            A1[node * NHEADS + h] = p1;
            A2[node * NHEADS + h] = p2;
        }
    }
}

// ---------------- K4: per-edge logits + LeakyReLU + segment max -------------
__global__ __launch_bounds__(256) void k_edge_logit(
    const int* __restrict__ ei, const float* __restrict__ P,
    const float* __restrict__ deter, const float* __restrict__ A1,
    const float* __restrict__ A2, const float* __restrict__ cvec,
    float* __restrict__ exp_e, unsigned* __restrict__ mx) {
    int e = blockIdx.x * 256 + threadIdx.x;
    if (e >= N_EDGES) return;
    int src = ei[e];
    int dst = ei[N_EDGES + e];
    float p = P[e], dt = deter[e];
    float4 a1lo = reinterpret_cast<const float4*>(A1 + (size_t)dst * NHEADS)[0];
    float4 a1hi = reinterpret_cast<const float4*>(A1 + (size_t)dst * NHEADS)[1];
    float4 a2lo = reinterpret_cast<const float4*>(A2 + (size_t)src * NHEADS)[0];
    float4 a2hi = reinterpret_cast<const float4*>(A2 + (size_t)src * NHEADS)[1];
    float a1v[8] = {a1lo.x, a1lo.y, a1lo.z, a1lo.w, a1hi.x, a1hi.y, a1hi.z, a1hi.w};
    float a2v[8] = {a2lo.x, a2lo.y, a2lo.z, a2lo.w, a2hi.x, a2hi.y, a2hi.z, a2hi.w};
    float lg[8];
    #pragma unroll
    for (int h = 0; h < NHEADS; ++h) {
        float l = a1v[h] + a2v[h] + p * cvec[h] + dt;
        l = (l >= 0.f) ? l : LEAKY * l;
        lg[h] = l;
        atomicMax(&mx[dst * NHEADS + h], mono(l));
    }
    float4* st = reinterpret_cast<float4*>(exp_e + (size_t)e * NHEADS);
    st[0] = make_float4(lg[0], lg[1], lg[2], lg[3]);
    st[1] = make_float4(lg[4], lg[5], lg[6], lg[7]);
}

// ---------------- K5: exp(logit - max), denom accumulation ------------------
__global__ __launch_bounds__(256) void k_edge_exp(
    const int* __restrict__ ei, const unsigned* __restrict__ mx,
    float* __restrict__ exp_e, float* __restrict__ denom) {
    int e = blockIdx.x * 256 + threadIdx.x;
    if (e >= N_EDGES) return;
    int dst = ei[N_EDGES + e];
    float4 l0 = reinterpret_cast<const float4*>(exp_e + (size_t)e * NHEADS)[0];
    float4 l1 = reinterpret_cast<const float4*>(exp_e + (size_t)e * NHEADS)[1];
    float lg[8] = {l0.x, l0.y, l0.z, l0.w, l1.x, l1.y, l1.z, l1.w};
    float ex[8];
    #pragma unroll
    for (int h = 0; h < NHEADS; ++h) {
        float m = unmono(mx[dst * NHEADS + h]);
        ex[h] = __expf(lg[h] - m);
        atomicAdd(&denom[dst * NHEADS + h], ex[h]);
    }
    float4* st = reinterpret_cast<float4*>(exp_e + (size_t)e * NHEADS);
    st[0] = make_float4(ex[0], ex[1], ex[2], ex[3]);
    st[1] = make_float4(ex[4], ex[5], ex[6], ex[7]);
}

// ---------------- K6: agg[dst] += alpha * V[src]  (atomic scatter) ----------
__global__ __launch_bounds__(256) void k_edge_agg(
    const int* __restrict__ ei, const float* __restrict__ exp_e,
    const float* __restrict__ denom, const float* __restrict__ V,
    float* __restrict__ agg) {
    int idx = blockIdx.x * 256 + threadIdx.x;
    int e = idx >> 7;
    int d = idx & 127;
    if (e >= N_EDGES) return;
    int src = ei[e];
    int dst = ei[N_EDGES + e];
    int h = d >> 4;
    float ex = exp_e[(size_t)e * NHEADS + h];
    float dn = denom[dst * NHEADS + h];
    float alpha = ex / (dn + 1e-12f);
    float v = V[(size_t)src * DIM + d];
    atomicAdd(&agg[(size_t)dst * DIM + d], alpha * v);
}

// ---------------- K7: out = agg@Wout^T + b + R, then LayerNorm --------------
__global__ __launch_bounds__(128) void k_out_ln(
    const float* __restrict__ agg, const float* __restrict__ R,
    const float* __restrict__ Wout, const float* __restrict__ bout,
    const float* __restrict__ ln_g, const float* __restrict__ ln_b,
    float* __restrict__ out) {
    __shared__ __align__(16) float As[NPB][DIM];
    __shared__ float outS[NPB][DIM + 1];
    __shared__ float mu_s[NPB], rs_s[NPB];
    int d = threadIdx.x;
    int n0 = blockIdx.x * NPB;
    #pragma unroll
    for (int i = 0; i < NPB; ++i) As[i][d] = agg[(size_t)(n0 + i) * DIM + d];
    __syncthreads();
    float acc[NPB];
    #pragma unroll
    for (int i = 0; i < NPB; ++i) acc[i] = 0.f;
    const float4* Wo4 = reinterpret_cast<const float4*>(Wout + (size_t)d * DIM);
    #pragma unroll 4
    for (int k4 = 0; k4 < DIM / 4; ++k4) {
        float4 w = Wo4[k4];
        #pragma unroll
        for (int i = 0; i < NPB; ++i) {
            float4 a = *reinterpret_cast<const float4*>(&As[i][k4 * 4]);
            acc[i] += a.x * w.x + a.y * w.y + a.z * w.z + a.w * w.w;
        }
    }
    float bo = bout[d];
    #pragma unroll
    for (int i = 0; i < NPB; ++i) {
        acc[i] += bo + R[(size_t)(n0 + i) * DIM + d];
        outS[i][d] = acc[i];
    }
    __syncthreads();
    if (d < NPB) {
        float s = 0.f, sq = 0.f;
        for (int k = 0; k < DIM; ++k) {
            float v = outS[d][k];
            s += v;
            sq += v * v;
        }
        float mu = s * (1.f / DIM);
        float var = sq * (1.f / DIM) - mu * mu;
        mu_s[d] = mu;
        rs_s[d] = rsqrtf(var + LN_EPS);
    }
    __syncthreads();
    float gd = ln_g[d], bd = ln_b[d];
    #pragma unroll
    for (int i = 0; i < NPB; ++i) {
        out[(size_t)(n0 + i) * DIM + d] = (acc[i] - mu_s[i]) * rs_s[i] * gd + bd;
    }
}

// ---------------------------------------------------------------------------
extern "C" void kernel_launch(void* const* d_in, const int* in_sizes, int n_in,
                              void* d_out, int out_size, void* d_ws, size_t ws_size,
                              hipStream_t stream) {
    const float* H      = (const float*)d_in[0];
    const int*   ei     = (const int*)d_in[1];
    const float* P      = (const float*)d_in[2];
    const float* deter  = (const float*)d_in[3];
    const float* W1     = (const float*)d_in[4];
    const float* W2     = (const float*)d_in[5];
    const float* W3     = (const float*)d_in[6];
    const float* W4     = (const float*)d_in[7];
    const float* Wv     = (const float*)d_in[8];
    const float* Wout_w = (const float*)d_in[9];
    const float* Wout_b = (const float*)d_in[10];
    const float* res_w  = (const float*)d_in[11];
    const float* res_b  = (const float*)d_in[12];
    const float* ln_g   = (const float*)d_in[13];
    const float* ln_b   = (const float*)d_in[14];

    float* ws = (float*)d_ws;
    const size_t ND = (size_t)N_NODES * DIM;      // 6,400,000
    const size_t NH8 = (size_t)N_NODES * NHEADS;  // 400,000
    const size_t EH = (size_t)N_EDGES * NHEADS;   // 6,400,000

    float*    agg   = ws;                         // ND
    float*    denom = agg + ND;                   // NH8
    unsigned* mx    = (unsigned*)(denom + NH8);   // NH8
    float*    exp_e = (float*)(mx + NH8);         // EH
    float*    A1    = exp_e + EH;                 // NH8
    float*    A2    = A1 + NH8;                   // NH8
    float*    Vbuf  = A2 + NH8;                   // ND
    float*    Rbuf  = Vbuf + ND;                  // ND
    float*    U1    = Rbuf + ND;                  // 1024
    float*    U2    = U1 + NHEADS * DIM;          // 1024
    float*    cvec  = U2 + NHEADS * DIM;          // 8

    // zero agg + denom + mx (contiguous prefix)
    hipMemsetAsync(d_ws, 0, (ND + 2 * NH8) * sizeof(float), stream);

    k_prep<<<NHEADS, DIM, 0, stream>>>(W1, W2, W3, W4, U1, U2, cvec);
    k_node_vr<<<N_NODES / NPB, DIM, 0, stream>>>(H, Wv, res_w, res_b, Vbuf, Rbuf);
    k_node_a<<<(N_NODES + 3) / 4, 256, 0, stream>>>(H, U1, U2, A1, A2);
    k_edge_logit<<<(N_EDGES + 255) / 256, 256, 0, stream>>>(ei, P, deter, A1, A2, cvec, exp_e, mx);
    k_edge_exp<<<(N_EDGES + 255) / 256, 256, 0, stream>>>(ei, mx, exp_e, denom);
    k_edge_agg<<<(size_t)N_EDGES * DIM / 256, 256, 0, stream>>>(ei, exp_e, denom, Vbuf, agg);
    k_out_ln<<<N_NODES / NPB, DIM, 0, stream>>>(agg, Rbuf, Wout_w, Wout_b, ln_g, ln_b, (float*)d_out);
}

// Round 2
// 599.276 us; speedup vs baseline: 2.0377x; 2.0377x over previous
//
#include <hip/hip_runtime.h>
#include <math.h>

#define N_NODES 50000
#define N_EDGES 800000
#define DIM 128
#define NHEADS 8
#define HDIM 16
#define LN_EPS 1e-5f
#define LEAKY 0.2f
#define NPB 16   // nodes per block for the node-level GEMM kernels

// ---------------- K1: U1 = W4@W1, U2 = W4@W2, c = W4@W3 (tiny) --------------
__global__ __launch_bounds__(128) void k_prep(
    const float* __restrict__ W1, const float* __restrict__ W2,
    const float* __restrict__ W3, const float* __restrict__ W4,
    float* __restrict__ U1, float* __restrict__ U2, float* __restrict__ c) {
    int h = blockIdx.x;       // 0..7
    int k = threadIdx.x;      // 0..127
    float a1 = 0.f, a2 = 0.f;
    for (int d = 0; d < DIM; ++d) {
        float w4 = W4[h * DIM + d];
        a1 += w4 * W1[d * DIM + k];
        a2 += w4 * W2[d * DIM + k];
    }
    U1[h * DIM + k] = a1;
    U2[h * DIM + k] = a2;
    __shared__ float red[DIM];
    red[k] = W4[h * DIM + k] * W3[k];
    __syncthreads();
    if (k == 0) {
        float s = 0.f;
        for (int i = 0; i < DIM; ++i) s += red[i];
        c[h] = s;
    }
}

// ---------------- K2: V = H@Wv^T ; A1 = H@U1^T ; A2 = H@U2^T ----------------
__global__ __launch_bounds__(128) void k_node_va(
    const float* __restrict__ H, const float* __restrict__ Wv,
    const float* __restrict__ U1, const float* __restrict__ U2,
    float* __restrict__ V, float* __restrict__ A1, float* __restrict__ A2) {
    __shared__ __align__(16) float Hs[NPB][DIM + 4];
    __shared__ float Us1[NHEADS * 130];   // stride 130 breaks bank aliasing
    __shared__ float Us2[NHEADS * 130];
    int d = threadIdx.x;
    int n0 = blockIdx.x * NPB;
    #pragma unroll
    for (int i = 0; i < NPB; ++i) Hs[i][d] = H[(size_t)(n0 + i) * DIM + d];
    #pragma unroll
    for (int r = 0; r < NHEADS; ++r) {
        Us1[r * 130 + d] = U1[r * DIM + d];
        Us2[r * 130 + d] = U2[r * DIM + d];
    }
    __syncthreads();
    // --- V phase: stream Wv row d, reuse Hs across 16 nodes ---
    float accv[NPB];
    #pragma unroll
    for (int i = 0; i < NPB; ++i) accv[i] = 0.f;
    const float4* Wv4 = reinterpret_cast<const float4*>(Wv + (size_t)d * DIM);
    #pragma unroll 4
    for (int k4 = 0; k4 < DIM / 4; ++k4) {
        float4 wv = Wv4[k4];
        #pragma unroll
        for (int i = 0; i < NPB; ++i) {
            float4 hh = *reinterpret_cast<const float4*>(&Hs[i][k4 * 4]);
            accv[i] += hh.x * wv.x + hh.y * wv.y + hh.z * wv.z + hh.w * wv.w;
        }
    }
    #pragma unroll
    for (int i = 0; i < NPB; ++i) V[(size_t)(n0 + i) * DIM + d] = accv[i];
    // --- A phase: thread (i = d>>3, h = d&7) does a full 128-dot from LDS ---
    int i = d >> 3, h = d & 7;
    float a1 = 0.f, a2 = 0.f;
    for (int k = 0; k < DIM; ++k) {
        float hv = Hs[i][k];
        a1 += hv * Us1[h * 130 + k];
        a2 += hv * Us2[h * 130 + k];
    }
    A1[(size_t)(n0 + i) * NHEADS + h] = a1;   // == A1[n0*8 + d] : coalesced
    A2[(size_t)(n0 + i) * NHEADS + h] = a2;
}

// ---------------- K3: degree histogram --------------------------------------
__global__ __launch_bounds__(256) void k_hist(
    const int* __restrict__ ei, int* __restrict__ deg) {
    int e = blockIdx.x * 256 + threadIdx.x;
    if (e < N_EDGES) atomicAdd(&deg[ei[N_EDGES + e]], 1);
}

// ---------------- K4: single-block exclusive scan ---------------------------
#define SCAN_T 1024
#define SCAN_CH 49   // ceil(50000/1024)
__global__ __launch_bounds__(SCAN_T) void k_scan(
    const int* __restrict__ deg, int* __restrict__ row_off, int* __restrict__ cursor) {
    __shared__ int sums[SCAN_T];
    int t = threadIdx.x;
    int base = t * SCAN_CH;
    int s = 0;
    for (int j = 0; j < SCAN_CH; ++j) {
        int idx = base + j;
        if (idx < N_NODES) s += deg[idx];
    }
    sums[t] = s;
    __syncthreads();
    for (int off = 1; off < SCAN_T; off <<= 1) {
        int v = (t >= off) ? sums[t - off] : 0;
        __syncthreads();
        sums[t] += v;
        __syncthreads();
    }
    int excl = (t == 0) ? 0 : sums[t - 1];
    for (int j = 0; j < SCAN_CH; ++j) {
        int idx = base + j;
        if (idx < N_NODES) {
            row_off[idx] = excl;
            cursor[idx] = excl;
            excl += deg[idx];
        }
    }
    if (t == 0) row_off[N_NODES] = sums[SCAN_T - 1];
}

// ---------------- K5: bucket edges by dst (CSR build) -----------------------
__global__ __launch_bounds__(256) void k_bucket(
    const int* __restrict__ ei, int* __restrict__ cursor, int2* __restrict__ pairs) {
    int e = blockIdx.x * 256 + threadIdx.x;
    if (e >= N_EDGES) return;
    int src = ei[e];
    int dst = ei[N_EDGES + e];
    int pos = atomicAdd(&cursor[dst], 1);
    pairs[pos] = make_int2(src, e);
}

// ---------------- K6: per-node softmax (no atomics) -------------------------
// wave per node; lane l -> head h=l&7, edge-subset sub=l>>3 (stride 8)
__global__ __launch_bounds__(256) void k_softmax(
    const int* __restrict__ row_off, const int2* __restrict__ pairs,
    const float* __restrict__ A1, const float* __restrict__ A2,
    const float* __restrict__ cvec, const float* __restrict__ P,
    const float* __restrict__ deter, float* __restrict__ ex_s,
    float* __restrict__ dninv) {
    int n = (blockIdx.x * 256 + threadIdx.x) >> 6;
    int l = threadIdx.x & 63;
    if (n >= N_NODES) return;
    int h = l & 7, sub = l >> 3;
    int start = row_off[n], end = row_off[n + 1];
    float a1 = A1[(size_t)n * NHEADS + h];
    float ch = cvec[h];
    float pm = -INFINITY;
    for (int j = start + sub; j < end; j += 8) {
        int2 pr = pairs[j];
        float lg = a1 + A2[(size_t)pr.x * NHEADS + h] + P[pr.y] * ch + deter[pr.y];
        lg = (lg >= 0.f) ? lg : LEAKY * lg;
        pm = fmaxf(pm, lg);
    }
    #pragma unroll
    for (int mask = 8; mask < 64; mask <<= 1) pm = fmaxf(pm, __shfl_xor(pm, mask, 64));
    float s = 0.f;
    for (int j = start + sub; j < end; j += 8) {
        int2 pr = pairs[j];
        float lg = a1 + A2[(size_t)pr.x * NHEADS + h] + P[pr.y] * ch + deter[pr.y];
        lg = (lg >= 0.f) ? lg : LEAKY * lg;
        float ex = __expf(lg - pm);
        s += ex;
        ex_s[(size_t)j * NHEADS + h] = ex;   // sorted order: fully coalesced
    }
    #pragma unroll
    for (int mask = 8; mask < 64; mask <<= 1) s += __shfl_xor(s, mask, 64);
    if (l < 8) dninv[(size_t)n * NHEADS + h] = 1.f / (s + 1e-12f);
}

// ---------------- K7: aggregation, gather-based (no atomics) ----------------
// wave per node; lane d owns dims d and d+64 (heads d>>4 and 4+(d>>4))
__global__ __launch_bounds__(256) void k_agg(
    const int* __restrict__ row_off, const int2* __restrict__ pairs,
    const float* __restrict__ ex_s, const float* __restrict__ V,
    const float* __restrict__ dninv, float* __restrict__ agg) {
    int n = (blockIdx.x * 256 + threadIdx.x) >> 6;
    int d = threadIdx.x & 63;
    if (n >= N_NODES) return;
    int h0 = d >> 4;
    float di0 = dninv[(size_t)n * NHEADS + h0];
    float di1 = dninv[(size_t)n * NHEADS + 4 + h0];
    int start = row_off[n], end = row_off[n + 1];
    float acc0 = 0.f, acc1 = 0.f;
    for (int j = start; j < end; ++j) {
        int src = pairs[j].x;
        float e0 = ex_s[(size_t)j * NHEADS + h0];
        float e1 = ex_s[(size_t)j * NHEADS + 4 + h0];
        float v0 = V[(size_t)src * DIM + d];
        float v1 = V[(size_t)src * DIM + 64 + d];
        acc0 += e0 * v0;
        acc1 += e1 * v1;
    }
    agg[(size_t)n * DIM + d] = acc0 * di0;
    agg[(size_t)n * DIM + 64 + d] = acc1 * di1;
}

// ---------------- K8: out = agg@Wout^T + b + (H@res_w^T + res_b), LayerNorm -
__global__ __launch_bounds__(128) void k_out_ln(
    const float* __restrict__ agg, const float* __restrict__ H,
    const float* __restrict__ Wout, const float* __restrict__ bout,
    const float* __restrict__ Wres, const float* __restrict__ bres,
    const float* __restrict__ ln_g, const float* __restrict__ ln_b,
    float* __restrict__ out) {
    __shared__ __align__(16) float As[NPB][DIM + 4];
    __shared__ __align__(16) float Hs[NPB][DIM + 4];
    __shared__ float outS[NPB][DIM + 1];
    __shared__ float mu_s[NPB], rs_s[NPB];
    int d = threadIdx.x;
    int n0 = blockIdx.x * NPB;
    #pragma unroll
    for (int i = 0; i < NPB; ++i) {
        As[i][d] = agg[(size_t)(n0 + i) * DIM + d];
        Hs[i][d] = H[(size_t)(n0 + i) * DIM + d];
    }
    __syncthreads();
    float acc[NPB];
    #pragma unroll
    for (int i = 0; i < NPB; ++i) acc[i] = 0.f;
    const float4* Wo4 = reinterpret_cast<const float4*>(Wout + (size_t)d * DIM);
    const float4* Wr4 = reinterpret_cast<const float4*>(Wres + (size_t)d * DIM);
    #pragma unroll 4
    for (int k4 = 0; k4 < DIM / 4; ++k4) {
        float4 wo = Wo4[k4];
        float4 wr = Wr4[k4];
        #pragma unroll
        for (int i = 0; i < NPB; ++i) {
            float4 a = *reinterpret_cast<const float4*>(&As[i][k4 * 4]);
            float4 hh = *reinterpret_cast<const float4*>(&Hs[i][k4 * 4]);
            acc[i] += a.x * wo.x + a.y * wo.y + a.z * wo.z + a.w * wo.w
                    + hh.x * wr.x + hh.y * wr.y + hh.z * wr.z + hh.w * wr.w;
        }
    }
    float bo = bout[d] + bres[d];
    #pragma unroll
    for (int i = 0; i < NPB; ++i) {
        acc[i] += bo;
        outS[i][d] = acc[i];
    }
    __syncthreads();
    if (d < NPB) {
        float s = 0.f, sq = 0.f;
        for (int k = 0; k < DIM; ++k) {
            float v = outS[d][k];
            s += v;
            sq += v * v;
        }
        float mu = s * (1.f / DIM);
        float var = sq * (1.f / DIM) - mu * mu;
        mu_s[d] = mu;
        rs_s[d] = rsqrtf(var + LN_EPS);
    }
    __syncthreads();
    float gd = ln_g[d], bd = ln_b[d];
    #pragma unroll
    for (int i = 0; i < NPB; ++i) {
        out[(size_t)(n0 + i) * DIM + d] = (acc[i] - mu_s[i]) * rs_s[i] * gd + bd;
    }
}

// ---------------------------------------------------------------------------
extern "C" void kernel_launch(void* const* d_in, const int* in_sizes, int n_in,
                              void* d_out, int out_size, void* d_ws, size_t ws_size,
                              hipStream_t stream) {
    const float* H      = (const float*)d_in[0];
    const int*   ei     = (const int*)d_in[1];
    const float* P      = (const float*)d_in[2];
    const float* deter  = (const float*)d_in[3];
    const float* W1     = (const float*)d_in[4];
    const float* W2     = (const float*)d_in[5];
    const float* W3     = (const float*)d_in[6];
    const float* W4     = (const float*)d_in[7];
    const float* Wv     = (const float*)d_in[8];
    const float* Wout_w = (const float*)d_in[9];
    const float* Wout_b = (const float*)d_in[10];
    const float* res_w  = (const float*)d_in[11];
    const float* res_b  = (const float*)d_in[12];
    const float* ln_g   = (const float*)d_in[13];
    const float* ln_b   = (const float*)d_in[14];

    float* ws = (float*)d_ws;
    const size_t ND  = (size_t)N_NODES * DIM;      // 6,400,000
    const size_t NH8 = (size_t)N_NODES * NHEADS;   // 400,000
    const size_t EH  = (size_t)N_EDGES * NHEADS;   // 6,400,000

    float* Vbuf  = ws;                  // ND
    float* ex_s  = Vbuf + ND;           // EH
    float* agg   = ex_s + EH;           // ND
    float* A1    = agg + ND;            // NH8
    float* A2    = A1 + NH8;            // NH8
    float* dninv = A2 + NH8;            // NH8
    float* U1    = dninv + NH8;         // 1024
    float* U2    = U1 + NHEADS * DIM;   // 1024
    float* cvec  = U2 + NHEADS * DIM;   // 8 (padded to 16)
    int*   ibase   = (int*)(cvec + 16);
    int2*  pairs   = (int2*)ibase;          // 2*E ints (8B-aligned offset)
    int*   deg     = ibase + 2 * N_EDGES;   // N
    int*   row_off = deg + N_NODES;         // N+1
    int*   cursor  = row_off + N_NODES + 1; // N
    // total ~22.2M words (~89 MB)

    hipMemsetAsync(deg, 0, N_NODES * sizeof(int), stream);

    k_prep<<<NHEADS, DIM, 0, stream>>>(W1, W2, W3, W4, U1, U2, cvec);
    k_node_va<<<N_NODES / NPB, DIM, 0, stream>>>(H, Wv, U1, U2, Vbuf, A1, A2);
    k_hist<<<(N_EDGES + 255) / 256, 256, 0, stream>>>(ei, deg);
    k_scan<<<1, SCAN_T, 0, stream>>>(deg, row_off, cursor);
    k_bucket<<<(N_EDGES + 255) / 256, 256, 0, stream>>>(ei, cursor, pairs);
    k_softmax<<<(N_NODES + 3) / 4, 256, 0, stream>>>(row_off, pairs, A1, A2, cvec, P, deter, ex_s, dninv);
    k_agg<<<(N_NODES + 3) / 4, 256, 0, stream>>>(row_off, pairs, ex_s, Vbuf, dninv, agg);
    k_out_ln<<<N_NODES / NPB, DIM, 0, stream>>>(agg, H, Wout_w, Wout_b, res_w, res_b, ln_g, ln_b, (float*)d_out);
}

// Round 3
// 509.914 us; speedup vs baseline: 2.3949x; 1.1752x over previous
//
#include <hip/hip_runtime.h>
#include <math.h>

#define N_NODES 50000
#define N_EDGES 800000
#define DIM 128
#define NHEADS 8
#define LN_EPS 1e-5f
#define LEAKY 0.2f
#define NPB 16     // nodes per block for node-level GEMM kernels
#define NSB 196    // ceil(N_NODES/256) scan blocks

// ---------------- K1: U1 = W4@W1, U2 = W4@W2, c = W4@W3 (tiny) --------------
__global__ __launch_bounds__(128) void k_prep(
    const float* __restrict__ W1, const float* __restrict__ W2,
    const float* __restrict__ W3, const float* __restrict__ W4,
    float* __restrict__ U1, float* __restrict__ U2, float* __restrict__ c) {
    int h = blockIdx.x;       // 0..7
    int k = threadIdx.x;      // 0..127
    float a1 = 0.f, a2 = 0.f;
    for (int d = 0; d < DIM; ++d) {
        float w4 = W4[h * DIM + d];
        a1 += w4 * W1[d * DIM + k];
        a2 += w4 * W2[d * DIM + k];
    }
    U1[h * DIM + k] = a1;
    U2[h * DIM + k] = a2;
    __shared__ float red[DIM];
    red[k] = W4[h * DIM + k] * W3[k];
    __syncthreads();
    if (k == 0) {
        float s = 0.f;
        for (int i = 0; i < DIM; ++i) s += red[i];
        c[h] = s;
    }
}

// ---------------- K2: V = H@Wv^T ; A1 = H@U1^T ; A2 = H@U2^T ----------------
__global__ __launch_bounds__(128) void k_node_va(
    const float* __restrict__ H, const float* __restrict__ Wv,
    const float* __restrict__ U1, const float* __restrict__ U2,
    float* __restrict__ V, float* __restrict__ A1, float* __restrict__ A2) {
    __shared__ __align__(16) float Hs[NPB][DIM + 4];
    __shared__ float Us1[NHEADS * 130];
    __shared__ float Us2[NHEADS * 130];
    int d = threadIdx.x;
    int n0 = blockIdx.x * NPB;
    #pragma unroll
    for (int i = 0; i < NPB; ++i) Hs[i][d] = H[(size_t)(n0 + i) * DIM + d];
    #pragma unroll
    for (int r = 0; r < NHEADS; ++r) {
        Us1[r * 130 + d] = U1[r * DIM + d];
        Us2[r * 130 + d] = U2[r * DIM + d];
    }
    __syncthreads();
    float accv[NPB];
    #pragma unroll
    for (int i = 0; i < NPB; ++i) accv[i] = 0.f;
    const float4* Wv4 = reinterpret_cast<const float4*>(Wv + (size_t)d * DIM);
    #pragma unroll 4
    for (int k4 = 0; k4 < DIM / 4; ++k4) {
        float4 wv = Wv4[k4];
        #pragma unroll
        for (int i = 0; i < NPB; ++i) {
            float4 hh = *reinterpret_cast<const float4*>(&Hs[i][k4 * 4]);
            accv[i] += hh.x * wv.x + hh.y * wv.y + hh.z * wv.z + hh.w * wv.w;
        }
    }
    #pragma unroll
    for (int i = 0; i < NPB; ++i) V[(size_t)(n0 + i) * DIM + d] = accv[i];
    int i = d >> 3, h = d & 7;
    float a1 = 0.f, a2 = 0.f;
    for (int k = 0; k < DIM; ++k) {
        float hv = Hs[i][k];
        a1 += hv * Us1[h * 130 + k];
        a2 += hv * Us2[h * 130 + k];
    }
    A1[(size_t)(n0 + i) * NHEADS + h] = a1;   // coalesced: A1[n0*8 + d]
    A2[(size_t)(n0 + i) * NHEADS + h] = a2;
}

// ---------------- K3: degree histogram --------------------------------------
__global__ __launch_bounds__(256) void k_hist(
    const int* __restrict__ ei, int* __restrict__ deg) {
    int e = blockIdx.x * 256 + threadIdx.x;
    if (e < N_EDGES) atomicAdd(&deg[ei[N_EDGES + e]], 1);
}

// ---------------- K4a: per-block partial sums of deg ------------------------
__global__ __launch_bounds__(256) void k_scan1(
    const int* __restrict__ deg, int* __restrict__ partial) {
    int t = threadIdx.x;
    int idx = blockIdx.x * 256 + t;
    int v = (idx < N_NODES) ? deg[idx] : 0;
    #pragma unroll
    for (int off = 32; off > 0; off >>= 1) v += __shfl_down(v, off, 64);
    __shared__ int ws_[4];
    if ((t & 63) == 0) ws_[t >> 6] = v;
    __syncthreads();
    if (t == 0) partial[blockIdx.x] = ws_[0] + ws_[1] + ws_[2] + ws_[3];
}

// ---------------- K4b: single-block scan of NSB partials --------------------
__global__ __launch_bounds__(256) void k_scan2(
    const int* __restrict__ partial, int* __restrict__ partial_off) {
    __shared__ int sh[256];
    int t = threadIdx.x;
    int v = (t < NSB) ? partial[t] : 0;
    sh[t] = v;
    __syncthreads();
    #pragma unroll
    for (int off = 1; off < 256; off <<= 1) {
        int u = (t >= off) ? sh[t - off] : 0;
        __syncthreads();
        sh[t] += u;
        __syncthreads();
    }
    if (t < NSB) partial_off[t] = sh[t] - v;   // exclusive
}

// ---------------- K4c: per-block local scan + global offset -----------------
__global__ __launch_bounds__(256) void k_scan3(
    const int* __restrict__ deg, const int* __restrict__ partial_off,
    int* __restrict__ row_off, int* __restrict__ cursor) {
    __shared__ int sh[256];
    int t = threadIdx.x;
    int idx = blockIdx.x * 256 + t;
    int v = (idx < N_NODES) ? deg[idx] : 0;
    sh[t] = v;
    __syncthreads();
    #pragma unroll
    for (int off = 1; off < 256; off <<= 1) {
        int u = (t >= off) ? sh[t - off] : 0;
        __syncthreads();
        sh[t] += u;
        __syncthreads();
    }
    int excl = sh[t] - v + partial_off[blockIdx.x];
    if (idx < N_NODES) {
        row_off[idx] = excl;
        cursor[idx] = excl;
    }
    if (idx == N_NODES - 1) row_off[N_NODES] = excl + v;   // == N_EDGES
}

// ---------------- K5: bucket edges by dst; record = (src, P, deter, _) ------
__global__ __launch_bounds__(256) void k_bucket(
    const int* __restrict__ ei, const float* __restrict__ P,
    const float* __restrict__ deter, int* __restrict__ cursor,
    float4* __restrict__ rec) {
    int e = blockIdx.x * 256 + threadIdx.x;
    if (e >= N_EDGES) return;
    int src = ei[e];
    int dst = ei[N_EDGES + e];
    int pos = atomicAdd(&cursor[dst], 1);
    rec[pos] = make_float4(__int_as_float(src), P[e], deter[e], 0.f);
}

// ---------------- K6: fused softmax + aggregation (single pass, no max) -----
// wave per node; lane d owns dims (2d, 2d+1) -> head h = d>>3
__global__ __launch_bounds__(256) void k_sm_agg(
    const int* __restrict__ row_off, const float4* __restrict__ rec,
    const float* __restrict__ A1, const float* __restrict__ A2,
    const float* __restrict__ cvec, const float2* __restrict__ V2,
    float2* __restrict__ agg2) {
    int n = (blockIdx.x * 256 + threadIdx.x) >> 6;
    int d = threadIdx.x & 63;
    if (n >= N_NODES) return;
    int h = d >> 3;
    float a1 = A1[(size_t)n * NHEADS + h];
    float ch = cvec[h];
    int start = row_off[n], end = row_off[n + 1];
    float s = 0.f;
    float accx = 0.f, accy = 0.f;
    float4 r = (start < end) ? rec[start] : make_float4(0.f, 0.f, 0.f, 0.f);
    for (int j = start; j < end; ++j) {
        float4 rn = (j + 1 < end) ? rec[j + 1] : r;   // prefetch next record
        int src = __float_as_int(r.x);
        float l = a1 + A2[(size_t)src * NHEADS + h] + r.y * ch + r.z;
        l = (l >= 0.f) ? l : LEAKY * l;
        float ex = __expf(l);
        s += ex;
        float2 v = V2[(size_t)src * (DIM / 2) + d];
        accx += ex * v.x;
        accy += ex * v.y;
        r = rn;
    }
    float inv = 1.f / (s + 1e-12f);
    agg2[(size_t)n * (DIM / 2) + d] = make_float2(accx * inv, accy * inv);
}

// ---------------- K7: out = agg@Wout^T + b + (H@res_w^T + res_b), LayerNorm -
__global__ __launch_bounds__(128) void k_out_ln(
    const float* __restrict__ agg, const float* __restrict__ H,
    const float* __restrict__ Wout, const float* __restrict__ bout,
    const float* __restrict__ Wres, const float* __restrict__ bres,
    const float* __restrict__ ln_g, const float* __restrict__ ln_b,
    float* __restrict__ out) {
    __shared__ __align__(16) float As[NPB][DIM + 4];
    __shared__ __align__(16) float Hs[NPB][DIM + 4];
    __shared__ float outS[NPB][DIM + 1];
    __shared__ float mu_s[NPB], rs_s[NPB];
    int d = threadIdx.x;
    int n0 = blockIdx.x * NPB;
    #pragma unroll
    for (int i = 0; i < NPB; ++i) {
        As[i][d] = agg[(size_t)(n0 + i) * DIM + d];
        Hs[i][d] = H[(size_t)(n0 + i) * DIM + d];
    }
    __syncthreads();
    float acc[NPB];
    #pragma unroll
    for (int i = 0; i < NPB; ++i) acc[i] = 0.f;
    const float4* Wo4 = reinterpret_cast<const float4*>(Wout + (size_t)d * DIM);
    const float4* Wr4 = reinterpret_cast<const float4*>(Wres + (size_t)d * DIM);
    #pragma unroll 4
    for (int k4 = 0; k4 < DIM / 4; ++k4) {
        float4 wo = Wo4[k4];
        float4 wr = Wr4[k4];
        #pragma unroll
        for (int i = 0; i < NPB; ++i) {
            float4 a = *reinterpret_cast<const float4*>(&As[i][k4 * 4]);
            float4 hh = *reinterpret_cast<const float4*>(&Hs[i][k4 * 4]);
            acc[i] += a.x * wo.x + a.y * wo.y + a.z * wo.z + a.w * wo.w
                    + hh.x * wr.x + hh.y * wr.y + hh.z * wr.z + hh.w * wr.w;
        }
    }
    float bo = bout[d] + bres[d];
    #pragma unroll
    for (int i = 0; i < NPB; ++i) {
        acc[i] += bo;
        outS[i][d] = acc[i];
    }
    __syncthreads();
    if (d < NPB) {
        float s = 0.f, sq = 0.f;
        for (int k = 0; k < DIM; ++k) {
            float v = outS[d][k];
            s += v;
            sq += v * v;
        }
        float mu = s * (1.f / DIM);
        float var = sq * (1.f / DIM) - mu * mu;
        mu_s[d] = mu;
        rs_s[d] = rsqrtf(var + LN_EPS);
    }
    __syncthreads();
    float gd = ln_g[d], bd = ln_b[d];
    #pragma unroll
    for (int i = 0; i < NPB; ++i) {
        out[(size_t)(n0 + i) * DIM + d] = (acc[i] - mu_s[i]) * rs_s[i] * gd + bd;
    }
}

// ---------------------------------------------------------------------------
extern "C" void kernel_launch(void* const* d_in, const int* in_sizes, int n_in,
                              void* d_out, int out_size, void* d_ws, size_t ws_size,
                              hipStream_t stream) {
    const float* H      = (const float*)d_in[0];
    const int*   ei     = (const int*)d_in[1];
    const float* P      = (const float*)d_in[2];
    const float* deter  = (const float*)d_in[3];
    const float* W1     = (const float*)d_in[4];
    const float* W2     = (const float*)d_in[5];
    const float* W3     = (const float*)d_in[6];
    const float* W4     = (const float*)d_in[7];
    const float* Wv     = (const float*)d_in[8];
    const float* Wout_w = (const float*)d_in[9];
    const float* Wout_b = (const float*)d_in[10];
    const float* res_w  = (const float*)d_in[11];
    const float* res_b  = (const float*)d_in[12];
    const float* ln_g   = (const float*)d_in[13];
    const float* ln_b   = (const float*)d_in[14];

    float* ws = (float*)d_ws;
    const size_t ND  = (size_t)N_NODES * DIM;      // 6,400,000
    const size_t NH8 = (size_t)N_NODES * NHEADS;   // 400,000

    float*  Vbuf = ws;                    // ND
    float*  agg  = Vbuf + ND;             // ND
    float*  A1   = agg + ND;              // NH8
    float*  A2   = A1 + NH8;              // NH8
    float*  U1   = A2 + NH8;              // 1024
    float*  U2   = U1 + NHEADS * DIM;     // 1024
    float*  cvec = U2 + NHEADS * DIM;     // 16
    float4* rec  = (float4*)(cvec + 16);  // E records (16B each; offset 16B-aligned)
    int* deg         = (int*)(rec + N_EDGES);   // N
    int* row_off     = deg + N_NODES;           // N+1
    int* cursor      = row_off + N_NODES + 1;   // N
    int* partial     = cursor + N_NODES;        // 256
    int* partial_off = partial + 256;           // 256
    // total ~17.2M words (~69 MB)

    hipMemsetAsync(deg, 0, N_NODES * sizeof(int), stream);

    k_prep<<<NHEADS, DIM, 0, stream>>>(W1, W2, W3, W4, U1, U2, cvec);
    k_node_va<<<N_NODES / NPB, DIM, 0, stream>>>(H, Wv, U1, U2, Vbuf, A1, A2);
    k_hist<<<(N_EDGES + 255) / 256, 256, 0, stream>>>(ei, deg);
    k_scan1<<<NSB, 256, 0, stream>>>(deg, partial);
    k_scan2<<<1, 256, 0, stream>>>(partial, partial_off);
    k_scan3<<<NSB, 256, 0, stream>>>(deg, partial_off, row_off, cursor);
    k_bucket<<<(N_EDGES + 255) / 256, 256, 0, stream>>>(ei, P, deter, cursor, rec);
    k_sm_agg<<<(N_NODES + 3) / 4, 256, 0, stream>>>(row_off, rec, A1, A2, cvec,
                                                    (const float2*)Vbuf, (float2*)agg);
    k_out_ln<<<N_NODES / NPB, DIM, 0, stream>>>(agg, H, Wout_w, Wout_b, res_w, res_b,
                                                ln_g, ln_b, (float*)d_out);
}

// Round 4
// 390.195 us; speedup vs baseline: 3.1296x; 1.3068x over previous
//
#include <hip/hip_runtime.h>
#include <hip/hip_fp16.h>
#include <math.h>

#define N_NODES 50000
#define N_EDGES 800000
#define DIM 128
#define NHEADS 8
#define LN_EPS 1e-5f
#define LEAKY 0.2f
#define NPB 16     // nodes per block for node-level GEMM kernels
#define NSB 196    // ceil(N_NODES/256) scan blocks

// ---------------- pack/unpack (P, deter) as half2 in one int ----------------
__device__ __forceinline__ int pack_pd(float p, float dt) {
    __half2 h = __floats2half2_rn(p, dt);
    int r; __builtin_memcpy(&r, &h, 4); return r;
}
__device__ __forceinline__ float2 unpack_pd(int v) {
    __half2 h; __builtin_memcpy(&h, &v, 4);
    return __half22float2(h);   // .x = P, .y = deter
}

// ---------------- K1: U1 = W4@W1, U2 = W4@W2, c = W4@W3 (tiny) --------------
__global__ __launch_bounds__(128) void k_prep(
    const float* __restrict__ W1, const float* __restrict__ W2,
    const float* __restrict__ W3, const float* __restrict__ W4,
    float* __restrict__ U1, float* __restrict__ U2, float* __restrict__ c) {
    int h = blockIdx.x;       // 0..7
    int k = threadIdx.x;      // 0..127
    float a1 = 0.f, a2 = 0.f;
    for (int d = 0; d < DIM; ++d) {
        float w4 = W4[h * DIM + d];
        a1 += w4 * W1[d * DIM + k];
        a2 += w4 * W2[d * DIM + k];
    }
    U1[h * DIM + k] = a1;
    U2[h * DIM + k] = a2;
    __shared__ float red[DIM];
    red[k] = W4[h * DIM + k] * W3[k];
    __syncthreads();
    if (k == 0) {
        float s = 0.f;
        for (int i = 0; i < DIM; ++i) s += red[i];
        c[h] = s;
    }
}

// ------- K2: Vh = fp16(H@Wv^T) ; A1 = H@U1^T ; A2 = H@U2^T ------------------
__global__ __launch_bounds__(128) void k_node_va(
    const float* __restrict__ H, const float* __restrict__ Wv,
    const float* __restrict__ U1, const float* __restrict__ U2,
    __half* __restrict__ Vh, float* __restrict__ A1, float* __restrict__ A2) {
    __shared__ __align__(16) float Hs[NPB][DIM + 4];
    __shared__ float Us1[NHEADS * 130];
    __shared__ float Us2[NHEADS * 130];
    int d = threadIdx.x;
    int n0 = blockIdx.x * NPB;
    #pragma unroll
    for (int i = 0; i < NPB; ++i) Hs[i][d] = H[(size_t)(n0 + i) * DIM + d];
    #pragma unroll
    for (int r = 0; r < NHEADS; ++r) {
        Us1[r * 130 + d] = U1[r * DIM + d];
        Us2[r * 130 + d] = U2[r * DIM + d];
    }
    __syncthreads();
    float accv[NPB];
    #pragma unroll
    for (int i = 0; i < NPB; ++i) accv[i] = 0.f;
    const float4* Wv4 = reinterpret_cast<const float4*>(Wv + (size_t)d * DIM);
    #pragma unroll 4
    for (int k4 = 0; k4 < DIM / 4; ++k4) {
        float4 wv = Wv4[k4];
        #pragma unroll
        for (int i = 0; i < NPB; ++i) {
            float4 hh = *reinterpret_cast<const float4*>(&Hs[i][k4 * 4]);
            accv[i] += hh.x * wv.x + hh.y * wv.y + hh.z * wv.z + hh.w * wv.w;
        }
    }
    #pragma unroll
    for (int i = 0; i < NPB; ++i)
        Vh[(size_t)(n0 + i) * DIM + d] = __float2half_rn(accv[i]);
    int i = d >> 3, h = d & 7;
    float a1 = 0.f, a2 = 0.f;
    for (int k = 0; k < DIM; ++k) {
        float hv = Hs[i][k];
        a1 += hv * Us1[h * 130 + k];
        a2 += hv * Us2[h * 130 + k];
    }
    A1[(size_t)(n0 + i) * NHEADS + h] = a1;   // coalesced: A1[n0*8 + d]
    A2[(size_t)(n0 + i) * NHEADS + h] = a2;
}

// ---------------- K3: degree histogram --------------------------------------
__global__ __launch_bounds__(256) void k_hist(
    const int* __restrict__ ei, int* __restrict__ deg) {
    int e = blockIdx.x * 256 + threadIdx.x;
    if (e < N_EDGES) atomicAdd(&deg[ei[N_EDGES + e]], 1);
}

// ---------------- K4a: per-block partial sums of deg ------------------------
__global__ __launch_bounds__(256) void k_scan1(
    const int* __restrict__ deg, int* __restrict__ partial) {
    int t = threadIdx.x;
    int idx = blockIdx.x * 256 + t;
    int v = (idx < N_NODES) ? deg[idx] : 0;
    #pragma unroll
    for (int off = 32; off > 0; off >>= 1) v += __shfl_down(v, off, 64);
    __shared__ int ws_[4];
    if ((t & 63) == 0) ws_[t >> 6] = v;
    __syncthreads();
    if (t == 0) partial[blockIdx.x] = ws_[0] + ws_[1] + ws_[2] + ws_[3];
}

// -------- K4b: per-block local scan; each block also scans the partials -----
__global__ __launch_bounds__(256) void k_scan3(
    const int* __restrict__ deg, const int* __restrict__ partial,
    int* __restrict__ row_off, int* __restrict__ cursor) {
    __shared__ int shp[256];
    __shared__ int sh[256];
    int t = threadIdx.x;
    // scan the NSB partials (inclusive) in every block — cheap, removes a launch
    int pv = (t < NSB) ? partial[t] : 0;
    shp[t] = pv;
    int idx = blockIdx.x * 256 + t;
    int v = (idx < N_NODES) ? deg[idx] : 0;
    sh[t] = v;
    __syncthreads();
    #pragma unroll
    for (int off = 1; off < 256; off <<= 1) {
        int u1 = (t >= off) ? shp[t - off] : 0;
        int u2 = (t >= off) ? sh[t - off] : 0;
        __syncthreads();
        shp[t] += u1;
        sh[t] += u2;
        __syncthreads();
    }
    int pofs = (blockIdx.x == 0) ? 0 : shp[blockIdx.x - 1];
    int excl = sh[t] - v + pofs;
    if (idx < N_NODES) {
        row_off[idx] = excl;
        cursor[idx] = excl;
    }
    if (idx == N_NODES - 1) row_off[N_NODES] = excl + v;   // == N_EDGES
}

// ---------------- K5: bucket edges by dst; record = (src, half2(P,deter)) ---
__global__ __launch_bounds__(256) void k_bucket(
    const int* __restrict__ ei, const float* __restrict__ P,
    const float* __restrict__ deter, int* __restrict__ cursor,
    int2* __restrict__ rec) {
    int e = blockIdx.x * 256 + threadIdx.x;
    if (e >= N_EDGES) return;
    int src = ei[e];
    int dst = ei[N_EDGES + e];
    int pos = atomicAdd(&cursor[dst], 1);
    rec[pos] = make_int2(src, pack_pd(P[e], deter[e]));
}

// ---------------- K6: fused softmax + aggregation (4x unrolled) -------------
// wave per node; lane d owns dims (2d, 2d+1) -> head h = d>>3
__global__ __launch_bounds__(256) void k_sm_agg(
    const int* __restrict__ row_off, const int2* __restrict__ rec,
    const float* __restrict__ A1, const float* __restrict__ A2,
    const float* __restrict__ cvec, const __half2* __restrict__ Vh2,
    float2* __restrict__ agg2) {
    int n = (blockIdx.x * 256 + threadIdx.x) >> 6;
    int d = threadIdx.x & 63;
    if (n >= N_NODES) return;
    int h = d >> 3;
    float a1 = A1[(size_t)n * NHEADS + h];
    float ch = cvec[h];
    int start = row_off[n], end = row_off[n + 1];
    float s = 0.f, accx = 0.f, accy = 0.f;
    int j = start;
    for (; j + 4 <= end; j += 4) {
        int2 r0 = rec[j], r1 = rec[j + 1], r2 = rec[j + 2], r3 = rec[j + 3];
        int s0 = r0.x, s1 = r1.x, s2 = r2.x, s3 = r3.x;
        float a20 = A2[(size_t)s0 * NHEADS + h];
        float a21 = A2[(size_t)s1 * NHEADS + h];
        float a22 = A2[(size_t)s2 * NHEADS + h];
        float a23 = A2[(size_t)s3 * NHEADS + h];
        __half2 v0 = Vh2[(size_t)s0 * (DIM / 2) + d];
        __half2 v1 = Vh2[(size_t)s1 * (DIM / 2) + d];
        __half2 v2 = Vh2[(size_t)s2 * (DIM / 2) + d];
        __half2 v3 = Vh2[(size_t)s3 * (DIM / 2) + d];
        float2 p0 = unpack_pd(r0.y), p1 = unpack_pd(r1.y);
        float2 p2 = unpack_pd(r2.y), p3 = unpack_pd(r3.y);
        float l0 = a1 + a20 + p0.x * ch + p0.y;
        float l1 = a1 + a21 + p1.x * ch + p1.y;
        float l2 = a1 + a22 + p2.x * ch + p2.y;
        float l3 = a1 + a23 + p3.x * ch + p3.y;
        l0 = (l0 >= 0.f) ? l0 : LEAKY * l0;
        l1 = (l1 >= 0.f) ? l1 : LEAKY * l1;
        l2 = (l2 >= 0.f) ? l2 : LEAKY * l2;
        l3 = (l3 >= 0.f) ? l3 : LEAKY * l3;
        float e0 = __expf(l0), e1 = __expf(l1), e2 = __expf(l2), e3 = __expf(l3);
        s += e0 + e1 + e2 + e3;
        float2 f0 = __half22float2(v0), f1 = __half22float2(v1);
        float2 f2 = __half22float2(v2), f3 = __half22float2(v3);
        accx += e0 * f0.x + e1 * f1.x + e2 * f2.x + e3 * f3.x;
        accy += e0 * f0.y + e1 * f1.y + e2 * f2.y + e3 * f3.y;
    }
    for (; j < end; ++j) {
        int2 r = rec[j];
        int src = r.x;
        float2 pd = unpack_pd(r.y);
        float l = a1 + A2[(size_t)src * NHEADS + h] + pd.x * ch + pd.y;
        l = (l >= 0.f) ? l : LEAKY * l;
        float ex = __expf(l);
        s += ex;
        float2 vf = __half22float2(Vh2[(size_t)src * (DIM / 2) + d]);
        accx += ex * vf.x;
        accy += ex * vf.y;
    }
    float inv = 1.f / (s + 1e-12f);
    agg2[(size_t)n * (DIM / 2) + d] = make_float2(accx * inv, accy * inv);
}

// ---------------- K7: out = agg@Wout^T + b + (H@res_w^T + res_b), LayerNorm -
__global__ __launch_bounds__(128) void k_out_ln(
    const float* __restrict__ agg, const float* __restrict__ H,
    const float* __restrict__ Wout, const float* __restrict__ bout,
    const float* __restrict__ Wres, const float* __restrict__ bres,
    const float* __restrict__ ln_g, const float* __restrict__ ln_b,
    float* __restrict__ out) {
    __shared__ __align__(16) float As[NPB][DIM + 4];
    __shared__ __align__(16) float Hs[NPB][DIM + 4];
    __shared__ float outS[NPB][DIM + 1];
    __shared__ float mu_s[NPB], rs_s[NPB];
    int d = threadIdx.x;
    int n0 = blockIdx.x * NPB;
    #pragma unroll
    for (int i = 0; i < NPB; ++i) {
        As[i][d] = agg[(size_t)(n0 + i) * DIM + d];
        Hs[i][d] = H[(size_t)(n0 + i) * DIM + d];
    }
    __syncthreads();
    float acc[NPB];
    #pragma unroll
    for (int i = 0; i < NPB; ++i) acc[i] = 0.f;
    const float4* Wo4 = reinterpret_cast<const float4*>(Wout + (size_t)d * DIM);
    const float4* Wr4 = reinterpret_cast<const float4*>(Wres + (size_t)d * DIM);
    #pragma unroll 4
    for (int k4 = 0; k4 < DIM / 4; ++k4) {
        float4 wo = Wo4[k4];
        float4 wr = Wr4[k4];
        #pragma unroll
        for (int i = 0; i < NPB; ++i) {
            float4 a = *reinterpret_cast<const float4*>(&As[i][k4 * 4]);
            float4 hh = *reinterpret_cast<const float4*>(&Hs[i][k4 * 4]);
            acc[i] += a.x * wo.x + a.y * wo.y + a.z * wo.z + a.w * wo.w
                    + hh.x * wr.x + hh.y * wr.y + hh.z * wr.z + hh.w * wr.w;
        }
    }
    float bo = bout[d] + bres[d];
    #pragma unroll
    for (int i = 0; i < NPB; ++i) {
        acc[i] += bo;
        outS[i][d] = acc[i];
    }
    __syncthreads();
    if (d < NPB) {
        float s = 0.f, sq = 0.f;
        for (int k = 0; k < DIM; ++k) {
            float v = outS[d][k];
            s += v;
            sq += v * v;
        }
        float mu = s * (1.f / DIM);
        float var = sq * (1.f / DIM) - mu * mu;
        mu_s[d] = mu;
        rs_s[d] = rsqrtf(var + LN_EPS);
    }
    __syncthreads();
    float gd = ln_g[d], bd = ln_b[d];
    #pragma unroll
    for (int i = 0; i < NPB; ++i) {
        out[(size_t)(n0 + i) * DIM + d] = (acc[i] - mu_s[i]) * rs_s[i] * gd + bd;
    }
}

// ---------------------------------------------------------------------------
extern "C" void kernel_launch(void* const* d_in, const int* in_sizes, int n_in,
                              void* d_out, int out_size, void* d_ws, size_t ws_size,
                              hipStream_t stream) {
    const float* H      = (const float*)d_in[0];
    const int*   ei     = (const int*)d_in[1];
    const float* P      = (const float*)d_in[2];
    const float* deter  = (const float*)d_in[3];
    const float* W1     = (const float*)d_in[4];
    const float* W2     = (const float*)d_in[5];
    const float* W3     = (const float*)d_in[6];
    const float* W4     = (const float*)d_in[7];
    const float* Wv     = (const float*)d_in[8];
    const float* Wout_w = (const float*)d_in[9];
    const float* Wout_b = (const float*)d_in[10];
    const float* res_w  = (const float*)d_in[11];
    const float* res_b  = (const float*)d_in[12];
    const float* ln_g   = (const float*)d_in[13];
    const float* ln_b   = (const float*)d_in[14];

    float* ws = (float*)d_ws;
    const size_t ND  = (size_t)N_NODES * DIM;      // 6,400,000
    const size_t NH8 = (size_t)N_NODES * NHEADS;   // 400,000

    __half* Vh  = (__half*)ws;            // ND halves = ND/2 floats
    float* agg  = ws + ND / 2;            // ND
    float* A1   = agg + ND;               // NH8
    float* A2   = A1 + NH8;               // NH8
    float* U1   = A2 + NH8;               // 1024
    float* U2   = U1 + NHEADS * DIM;      // 1024
    float* cvec = U2 + NHEADS * DIM;      // 16
    int2*  rec  = (int2*)(cvec + 16);     // E records (8B each)
    int* deg     = (int*)(rec + N_EDGES); // N
    int* row_off = deg + N_NODES;         // N+1
    int* cursor  = row_off + N_NODES + 1; // N
    int* partial = cursor + N_NODES;      // 256
    // total ~13.9M words (~56 MB)

    hipMemsetAsync(deg, 0, N_NODES * sizeof(int), stream);

    k_prep<<<NHEADS, DIM, 0, stream>>>(W1, W2, W3, W4, U1, U2, cvec);
    k_node_va<<<N_NODES / NPB, DIM, 0, stream>>>(H, Wv, U1, U2, Vh, A1, A2);
    k_hist<<<(N_EDGES + 255) / 256, 256, 0, stream>>>(ei, deg);
    k_scan1<<<NSB, 256, 0, stream>>>(deg, partial);
    k_scan3<<<NSB, 256, 0, stream>>>(deg, partial, row_off, cursor);
    k_bucket<<<(N_EDGES + 255) / 256, 256, 0, stream>>>(ei, P, deter, cursor, rec);
    k_sm_agg<<<(N_NODES + 3) / 4, 256, 0, stream>>>(row_off, rec, A1, A2, cvec,
                                                    (const __half2*)Vh, (float2*)agg);
    k_out_ln<<<N_NODES / NPB, DIM, 0, stream>>>(agg, H, Wout_w, Wout_b, res_w, res_b,
                                                ln_g, ln_b, (float*)d_out);
}